// Round 5
// baseline (150.294 us; speedup 1.0000x reference)
//
#include <hip/hip_runtime.h>

// Net_3152505995417: tiny GNN forward (N=116, E=6670, HID=64, EDIM=5).
// Algebraic collapses (exact, absmax=0 since R1):
//  * node_conv: out = D @ (Hv@W) + b, D[i,j] = d[eid(i,j)] off-diag (symmetric).
//  * edge_conv: out[e=(a,b),k] = dv[a]*(S[a,k]-Gp[e,k]) + dv[b]*(S[b,k]-Gp[e,k]) + be,
//      Gp[f] = G[f]/(max(dv[c],dv[d],0)+eps) for f=(c,d), S[i] = sum_{f∋i} Gp[f].
// R5: fence-free synchronization. R3/R4 post-mortem: ~12.6us/barrier is the
//   __threadfence() pair (buffer_wbl2+buffer_inv L2 walks, 29 blocks x 5
//   barriers), NOT arrival mechanics (R4 flag-array changed nothing). Fix:
//   every cross-block datum is stored/loaded with RELAXED+AGENT atomics
//   (global sc1 -> write-through to coherence point, loads bypass stale XCD
//   L2) -- the same path the R4 flags already used successfully. Barrier =
//   vmcnt drain (__syncthreads) + flag store + direct 29-flag poll. No cache
//   maintenance instructions anywhere.

#define NN   116
#define EE   6670
#define HID  64
#define EDIM 5
#define OUTD 4
#define ENC  122
#define EPSF 1e-10f
#define NH   (NN*HID)   // 7424
#define NB   29         // blocks
#define FSTR 16         // flag stride in uints (64B cacheline)

__device__ __forceinline__ int eid_ij(int i, int j) {
    int a = i < j ? i : j;
    int b = i < j ? j : i;
    return a*NN - ((a*(a+1)) >> 1) + (b - a - 1);   // triu k=1 row-major
}

// ---- coherent (agent-scope, relaxed) scalar/pair access helpers ----
__device__ __forceinline__ void stG(float* p, float v) {
    __hip_atomic_store(p, v, __ATOMIC_RELAXED, __HIP_MEMORY_SCOPE_AGENT);
}
__device__ __forceinline__ float ldG(const float* p) {
    return __hip_atomic_load(p, __ATOMIC_RELAXED, __HIP_MEMORY_SCOPE_AGENT);
}
__device__ __forceinline__ float2 ldG2(const float* p) {     // p 8B-aligned
    unsigned long long u = __hip_atomic_load((const unsigned long long*)p,
                                             __ATOMIC_RELAXED, __HIP_MEMORY_SCOPE_AGENT);
    float2 r; __builtin_memcpy(&r, &u, 8); return r;
}

// Fence-free grid barrier: drain vmem, publish epoch, every block polls all
// NB flags (lane l spins on flag l; wave reconverges when all exit).
__device__ __forceinline__ void gridbar(unsigned* flags, unsigned ep) {
    asm volatile("s_waitcnt vmcnt(0)" ::: "memory");
    __syncthreads();    // compiler drains vmcnt/lgkmcnt for every wave before s_barrier
    if (threadIdx.x == 0)
        __hip_atomic_store(flags + blockIdx.x*FSTR, ep,
                           __ATOMIC_RELAXED, __HIP_MEMORY_SCOPE_AGENT);
    if (threadIdx.x < NB) {
        while (__hip_atomic_load(flags + threadIdx.x*FSTR,
                                 __ATOMIC_RELAXED, __HIP_MEMORY_SCOPE_AGENT) < ep)
            __builtin_amdgcn_s_sleep(1);
    }
    __syncthreads();
}

__global__ __launch_bounds__(256) void fused(
    const float* __restrict__ enc, const float* __restrict__ ea,
    const int* __restrict__ eidx,
    const float* __restrict__ W_enc, const float* __restrict__ b_enc,
    const float* __restrict__ W1, const float* __restrict__ b1,
    const float* __restrict__ p1, const float* __restrict__ We,
    const float* __restrict__ be, const float* __restrict__ pe,
    const float* __restrict__ W2, const float* __restrict__ b2,
    const float* __restrict__ p2, const float* __restrict__ Wl,
    const float* __restrict__ bl,
    float* __restrict__ Y1, float* __restrict__ Y2,
    float* __restrict__ d1, float* __restrict__ d2,
    float* __restrict__ G,  float* __restrict__ dv,
    float* __restrict__ S,  float* __restrict__ P,
    unsigned* __restrict__ flags,
    float* __restrict__ out)
{
    __shared__ __align__(16) float sY[NH];     // 29696 B (Y1, then Y2)
    __shared__ __align__(16) float sD[EE];     // 26680 B (d1, then d2)
    __shared__ float sRow[4*HID];              // x-rows / dv cache / pool partials
    const int tid  = threadIdx.x;
    const int w    = tid >> 6, lane = tid & 63;
    const int node = blockIdx.x*4 + w;         // 0..115 (29*4=116, always valid)
    const int gt   = blockIdx.x*256 + tid;     // 0..7423

    // ---- Stage A: X=enc@W_enc+b_enc -> Y1=X@W1 (wave per node); d1, G (grid-strided); zero P.
    {
        float x = b_enc[lane];
        const float* er = enc + node*ENC;
        #pragma unroll 4
        for (int k = 0; k < ENC; ++k) x = fmaf(er[k], W_enc[k*HID + lane], x);
        sRow[w*HID + lane] = x;
        __syncthreads();
        float y = 0.f;
        const float* xr = sRow + w*HID;
        #pragma unroll 8
        for (int k = 0; k < HID; ++k) y = fmaf(xr[k], W1[k*HID + lane], y);
        stG(Y1 + node*HID + lane, y);

        for (int u = gt; u < EE + EE*EDIM; u += NB*256) {
            if (u < EE) {
                const float* r = ea + u*EDIM;
                float a0 = 0.f;
                #pragma unroll
                for (int k = 0; k < EDIM; ++k) a0 = fmaf(r[k], p1[k], a0);
                stG(d1 + u, a0);
            } else {
                int idx = u - EE;
                int e = idx / EDIM, k = idx - e*EDIM;
                const float* r = ea + e*EDIM;
                float a0 = 0.f;
                #pragma unroll
                for (int m = 0; m < EDIM; ++m) a0 = fmaf(fmaxf(r[m], 0.f), We[m*EDIM + k], a0);
                stG(G + idx, a0);
            }
        }
        if (gt < HID) stG(P + gt, 0.f);
    }
    gridbar(flags, 1u);

    // ---- Stage B: x2 = relu(D1@Y1 + b1); dv = x2@pe; Y2 = x2@W2. LDS-staged, branchless.
    {
        float2* sY2p = (float2*)sY;
        for (int u = tid; u < NH/2; u += 256) sY2p[u] = ldG2(Y1 + 2*u);
        float2* sD2p = (float2*)sD;
        for (int u = tid; u < EE/2; u += 256) sD2p[u] = ldG2(d1 + 2*u);
        __syncthreads();
        float acc = b1[lane];
        #pragma unroll 4
        for (int j = 0; j < NN; ++j) {
            int jj = (j == node) ? (j ^ 1) : j;
            float wgt = (j == node) ? 0.f : sD[eid_ij(node, jj)];
            acc = fmaf(wgt, sY[jj*HID + lane], acc);
        }
        float v = fmaxf(acc, 0.f);
        float r = v * pe[lane];
        #pragma unroll
        for (int off = 32; off > 0; off >>= 1) r += __shfl_xor(r, off, 64);
        if (lane == 0) stG(dv + node, r);
        __syncthreads();                 // sRow reuse (x-row slot)
        sRow[w*HID + lane] = v;
        __syncthreads();
        float y = 0.f;
        const float* xr = sRow + w*HID;
        #pragma unroll 8
        for (int k = 0; k < HID; ++k) y = fmaf(xr[k], W2[k*HID + lane], y);
        stG(Y2 + node*HID + lane, y);
    }
    gridbar(flags, 2u);

    // ---- Stage C: S[i,k] = sum_{j!=i} G[eid(i,j),k]/(max(dv[i],dv[j],0)+eps).
    //      dv cached in sRow; 580 (i,k) pairs = 116 waves x 5; lanes split j.
    {
        if (tid < NN) sRow[tid] = ldG(dv + tid);
        __syncthreads();
        #pragma unroll
        for (int rep = 0; rep < EDIM; ++rep) {
            int p = node + rep*NN;              // 0..579
            int i = p / EDIM, k = p - i*EDIM;
            float di = sRow[i];
            float acc = 0.f;
            #pragma unroll
            for (int half = 0; half < 2; ++half) {
                int j = lane + half*64;
                if (j < NN && j != i) {
                    float cm = fmaxf(fmaxf(di, sRow[j]), 0.f) + EPSF;
                    acc += ldG(G + eid_ij(i, j)*EDIM + k) / cm;
                }
            }
            #pragma unroll
            for (int off = 32; off > 0; off >>= 1) acc += __shfl_xor(acc, off, 64);
            if (lane == 0) stG(S + p, acc);
        }
    }
    gridbar(flags, 3u);

    // ---- Stage D: per-edge d2 (thread per edge; dv still cached in sRow).
    if (gt < EE) {
        const int a = eidx[gt], b = eidx[EE + gt];
        const float da = sRow[a], db = sRow[b];
        const float rc = 1.f / (fmaxf(fmaxf(da, db), 0.f) + EPSF);
        float acc = 0.f;
        #pragma unroll
        for (int kk = 0; kk < EDIM; ++kk) {
            float gp = ldG(G + gt*EDIM + kk) * rc;
            float v = fmaf(da, ldG(S + a*EDIM + kk) - gp,
                      fmaf(db, ldG(S + b*EDIM + kk) - gp, be[kk]));
            acc = fmaf(fmaxf(v, 0.f), p2[kk], acc);
        }
        stG(d2 + gt, acc);
    }
    gridbar(flags, 4u);

    // ---- Stage E: x3 = D2@Y2 + b2; block-partial pool -> atomicAdd P.
    {
        float2* sY2p = (float2*)sY;
        for (int u = tid; u < NH/2; u += 256) sY2p[u] = ldG2(Y2 + 2*u);
        float2* sD2p = (float2*)sD;
        for (int u = tid; u < EE/2; u += 256) sD2p[u] = ldG2(d2 + 2*u);
        __syncthreads();
        float acc = b2[lane];
        #pragma unroll 4
        for (int j = 0; j < NN; ++j) {
            int jj = (j == node) ? (j ^ 1) : j;
            float wgt = (j == node) ? 0.f : sD[eid_ij(node, jj)];
            acc = fmaf(wgt, sY[jj*HID + lane], acc);
        }
        sRow[w*HID + lane] = acc;
        __syncthreads();
        if (w == 0) {
            float s4v = sRow[lane] + sRow[HID + lane] + sRow[2*HID + lane] + sRow[3*HID + lane];
            atomicAdd(&P[lane], s4v);    // device-scope RMW at coherence point
        }
    }
    gridbar(flags, 5u);

    // ---- Stage F: out = (P/N) @ Wl + bl (block 0, wave 0).
    if (blockIdx.x == 0 && w == 0) {
        float val = ldG(P + lane) * (1.0f / NN);
        float res[OUTD];
        #pragma unroll
        for (int o = 0; o < OUTD; ++o) {
            float r = val * Wl[lane*OUTD + o];
            #pragma unroll
            for (int off = 32; off > 0; off >>= 1) r += __shfl_xor(r, off, 64);
            res[o] = r;
        }
        if (lane < OUTD) out[lane] = res[lane] + bl[lane];   // dispatch-release covers host visibility
    }
}

extern "C" void kernel_launch(void* const* d_in, const int* in_sizes, int n_in,
                              void* d_out, int out_size, void* d_ws, size_t ws_size,
                              hipStream_t stream)
{
    const float* enc   = (const float*)d_in[0];
    const float* ea    = (const float*)d_in[1];
    const int*   eidx  = (const int*)  d_in[2];
    const float* W_enc = (const float*)d_in[3];
    const float* b_enc = (const float*)d_in[4];
    const float* W1    = (const float*)d_in[5];
    const float* b1    = (const float*)d_in[6];
    const float* p1    = (const float*)d_in[7];
    const float* We    = (const float*)d_in[8];
    const float* be    = (const float*)d_in[9];
    const float* pe    = (const float*)d_in[10];
    const float* W2    = (const float*)d_in[11];
    const float* b2    = (const float*)d_in[12];
    const float* p2    = (const float*)d_in[13];
    const float* Wl    = (const float*)d_in[14];
    const float* bl    = (const float*)d_in[15];
    float* ws = (float*)d_ws;

    // Workspace layout (floats, 16B-aligned chunks):
    float* Y1 = ws;                    // 7424
    float* Y2 = ws + 7424;             // 7424
    float* d1 = ws + 14848;            // 6670 -> pad 6672
    float* d2 = ws + 21520;            // 6672
    float* G  = ws + 28192;            // 33350 -> pad 33352
    float* dv = ws + 61544;            // 116 -> pad 120
    float* S  = ws + 61664;            // 580 -> pad 584
    float* P  = ws + 62248;            // 64 -> pad 88 (to 64B-aligned 62336)
    unsigned* flags = (unsigned*)(ws + 62336);  // NB*FSTR uints, 64B-spaced
    float* out = (float*)d_out;

    hipMemsetAsync(flags, 0, NB * FSTR * sizeof(unsigned), stream);
    fused<<<NB, 256, 0, stream>>>(enc, ea, eidx, W_enc, b_enc, W1, b1, p1, We,
                                  be, pe, W2, b2, p2, Wl, bl,
                                  Y1, Y2, d1, d2, G, dv, S, P, flags, out);
}

// Round 6
// 145.272 us; speedup vs baseline: 1.0346x; 1.0346x over previous
//
#include <hip/hip_runtime.h>

// Net_3152505995417: tiny GNN forward (N=116, E=6670, HID=64, EDIM=5).
// Algebraic collapses (exact, absmax=0 since R1):
//  * node_conv: out = D @ (Hv@W) + b, D[i,j] = d[eid(i,j)] off-diag (symmetric).
//  * edge_conv: out[e=(a,b),k] = dv[a]*(S[a,k]-Gp[e,k]) + dv[b]*(S[b,k]-Gp[e,k]) + be,
//      Gp[f] = G[f]/(max(dv[c],dv[d],0)+eps) for f=(c,d), S[i] = sum_{f∋i} Gp[f].
// R6: BODY-only change (R5 barrier kept verbatim — controlled experiment).
//   R3/R4/R5 falsified barrier theories; the ~60us is latency CHAINS in the
//   body: unroll-4 global-load fma loops (W_enc 122-chain ~15us, W1/W2
//   64-chains ~6us each) + 67K scattered 4B G reads. Fixes:
//   (1) all GEMM weights burst-staged to LDS (independent float4 loads,
//       pipelined) with per-stage LDS overlays; compute reads LDS only.
//   (2) stage C edge-centric: G relaid [EDIM][EEP] column-major (coalesced),
//       per-block partial S in LDS (ds_add_f32), written to private Spart
//       column — no global atomics; stage D reduces 29 columns (pipelined).
//   (3) pooling via Ppart[64][32] private columns, reduced in stage F.

#define NN   116
#define EE   6670
#define EEP  6672       // padded edge stride (16B align)
#define HID  64
#define EDIM 5
#define OUTD 4
#define ENC  122
#define EPSF 1e-10f
#define NH   (NN*HID)   // 7424
#define NB   29         // blocks
#define FSTR 16         // flag stride in uints (64B cacheline)

__device__ __forceinline__ int eid_ij(int i, int j) {
    int a = i < j ? i : j;
    int b = i < j ? j : i;
    return a*NN - ((a*(a+1)) >> 1) + (b - a - 1);   // triu k=1 row-major
}

// ---- coherent (agent-scope, relaxed) access helpers: bypass non-coherent XCD L2 ----
__device__ __forceinline__ void stG(float* p, float v) {
    __hip_atomic_store(p, v, __ATOMIC_RELAXED, __HIP_MEMORY_SCOPE_AGENT);
}
__device__ __forceinline__ float ldG(const float* p) {
    return __hip_atomic_load(p, __ATOMIC_RELAXED, __HIP_MEMORY_SCOPE_AGENT);
}
__device__ __forceinline__ float2 ldG2(const float* p) {     // p 8B-aligned
    unsigned long long u = __hip_atomic_load((const unsigned long long*)p,
                                             __ATOMIC_RELAXED, __HIP_MEMORY_SCOPE_AGENT);
    float2 r; __builtin_memcpy(&r, &u, 8); return r;
}

// Fence-free grid barrier (R5 verbatim): drain vmem, publish epoch, poll all flags.
__device__ __forceinline__ void gridbar(unsigned* flags, unsigned ep) {
    asm volatile("s_waitcnt vmcnt(0)" ::: "memory");
    __syncthreads();
    if (threadIdx.x == 0)
        __hip_atomic_store(flags + blockIdx.x*FSTR, ep,
                           __ATOMIC_RELAXED, __HIP_MEMORY_SCOPE_AGENT);
    if (threadIdx.x < NB) {
        while (__hip_atomic_load(flags + threadIdx.x*FSTR,
                                 __ATOMIC_RELAXED, __HIP_MEMORY_SCOPE_AGENT) < ep)
            __builtin_amdgcn_s_sleep(1);
    }
    __syncthreads();
}

__global__ __launch_bounds__(256) void fused(
    const float* __restrict__ enc, const float* __restrict__ ea,
    const int* __restrict__ eidx,
    const float* __restrict__ W_enc, const float* __restrict__ b_enc,
    const float* __restrict__ W1, const float* __restrict__ b1,
    const float* __restrict__ p1, const float* __restrict__ We,
    const float* __restrict__ be, const float* __restrict__ pe,
    const float* __restrict__ W2, const float* __restrict__ b2,
    const float* __restrict__ p2, const float* __restrict__ Wl,
    const float* __restrict__ bl,
    float* __restrict__ Y1, float* __restrict__ Y2,
    float* __restrict__ d1, float* __restrict__ d2,
    float* __restrict__ G,  float* __restrict__ dv,
    float* __restrict__ Spart, float* __restrict__ Ppart,
    unsigned* __restrict__ flags,
    float* __restrict__ out)
{
    // Overlaid LDS: stage A = [W_enc | W1 | enc rows]; B/E = [Y | d]; B-tail = [Y | W2].
    __shared__ __align__(16) float sBuf[14100];   // 56400 B
    __shared__ float sRow[4*HID];                 // per-wave x rows / pool partials
    __shared__ float sDV[NN];                     // dv cache (stages C,D)
    __shared__ float sS[NN*EDIM];                 // partial/final S (stages C,D)
    const int tid  = threadIdx.x;
    const int w    = tid >> 6, lane = tid & 63;
    const int node = blockIdx.x*4 + w;            // 0..115 (29*4=116)
    const int gt   = blockIdx.x*256 + tid;        // 0..7423

    // ---- Stage A: X=enc@W_enc+b_enc -> Y1=X@W1 (weights in LDS); d1, G[col-major].
    {
        float* sWenc = sBuf;            // 122*64 = 7808
        float* sW1   = sBuf + 7808;     // 64*64  = 4096
        float* sEnc  = sBuf + 11904;    // 4*122  = 488
        {
            const float4* g4 = (const float4*)W_enc; float4* s4 = (float4*)sWenc;
            for (int u = tid; u < 7808/4; u += 256) s4[u] = g4[u];
        }
        {
            const float4* g4 = (const float4*)W1; float4* s4 = (float4*)sW1;
            for (int u = tid; u < 4096/4; u += 256) s4[u] = g4[u];
        }
        {
            const float4* g4 = (const float4*)(enc + blockIdx.x*4*ENC);  // 1952B blocks
            float4* s4 = (float4*)sEnc;
            for (int u = tid; u < 488/4; u += 256) s4[u] = g4[u];
        }
        __syncthreads();
        float x = b_enc[lane];
        const float* er = sEnc + w*ENC;
        #pragma unroll 8
        for (int k = 0; k < ENC; ++k) x = fmaf(er[k], sWenc[k*HID + lane], x);
        sRow[w*HID + lane] = x;         // same-wave LDS bounce (no cross-wave dep)
        float y = 0.f;
        const float* xr = sRow + w*HID;
        #pragma unroll 8
        for (int k = 0; k < HID; ++k) y = fmaf(xr[k], sW1[k*HID + lane], y);
        stG(Y1 + node*HID + lane, y);

        // thread-per-edge: d1 = ea@p1 ; G[k][e] = (relu(ea)@We)[k]  (col-major, coalesced)
        for (int e = gt; e < EE; e += NB*256) {
            const float* r = ea + e*EDIM;
            float r0 = r[0], r1 = r[1], r2 = r[2], r3 = r[3], r4 = r[4];
            float a0 = r0*p1[0] + r1*p1[1] + r2*p1[2] + r3*p1[3] + r4*p1[4];
            stG(d1 + e, a0);
            float q0 = fmaxf(r0,0.f), q1 = fmaxf(r1,0.f), q2 = fmaxf(r2,0.f),
                  q3 = fmaxf(r3,0.f), q4 = fmaxf(r4,0.f);
            #pragma unroll
            for (int k = 0; k < EDIM; ++k) {
                float g = q0*We[0*EDIM+k] + q1*We[1*EDIM+k] + q2*We[2*EDIM+k]
                        + q3*We[3*EDIM+k] + q4*We[4*EDIM+k];
                stG(G + k*EEP + e, g);
            }
        }
    }
    gridbar(flags, 1u);

    // ---- Stage B: x2 = relu(D1@Y1 + b1); dv = x2@pe; Y2 = x2@W2 (W2 in LDS).
    {
        float* sY = sBuf;               // 7424
        float* sD = sBuf + 7424;        // 6670
        float2* sY2p = (float2*)sY;
        for (int u = tid; u < NH/2; u += 256) sY2p[u] = ldG2(Y1 + 2*u);
        float2* sD2p = (float2*)sD;
        for (int u = tid; u < EE/2; u += 256) sD2p[u] = ldG2(d1 + 2*u);
        __syncthreads();
        float acc = b1[lane];
        #pragma unroll 4
        for (int j = 0; j < NN; ++j) {
            int jj = (j == node) ? (j ^ 1) : j;
            float wgt = (j == node) ? 0.f : sD[eid_ij(node, jj)];
            acc = fmaf(wgt, sY[jj*HID + lane], acc);
        }
        float v = fmaxf(acc, 0.f);
        float r = v * pe[lane];
        #pragma unroll
        for (int off = 32; off > 0; off >>= 1) r += __shfl_xor(r, off, 64);
        if (lane == 0) stG(dv + node, r);
        sRow[w*HID + lane] = v;          // own row only
        __syncthreads();                 // all waves done with sD before overwrite
        float* sW2 = sBuf + 7424;        // overlay W2 onto dead d1 space
        {
            const float4* g4 = (const float4*)W2; float4* s4 = (float4*)sW2;
            for (int u = tid; u < 4096/4; u += 256) s4[u] = g4[u];
        }
        __syncthreads();
        float y = 0.f;
        const float* xr = sRow + w*HID;
        #pragma unroll 8
        for (int k = 0; k < HID; ++k) y = fmaf(xr[k], sW2[k*HID + lane], y);
        stG(Y2 + node*HID + lane, y);
    }
    gridbar(flags, 2u);

    // ---- Stage C: edge-centric partial S. sS[i,k] += G[k][e]/cm(e) for i in {a,b}.
    {
        if (tid < NN) sDV[tid] = ldG(dv + tid);
        for (int u = tid; u < NN*EDIM; u += 256) sS[u] = 0.f;
        __syncthreads();
        for (int e = gt; e < EE; e += NB*256) {
            int a = eidx[e], b = eidx[EE + e];
            float da = sDV[a], db = sDV[b];
            float rc = 1.f / (fmaxf(fmaxf(da, db), 0.f) + EPSF);
            #pragma unroll
            for (int k = 0; k < EDIM; ++k) {
                float g = ldG(G + k*EEP + e) * rc;       // coalesced across lanes
                atomicAdd(&sS[a*EDIM + k], g);           // ds_add_f32
                atomicAdd(&sS[b*EDIM + k], g);
            }
        }
        __syncthreads();
        for (int u = tid; u < NN*EDIM; u += 256)
            stG(Spart + u*32 + blockIdx.x, sS[u]);       // private column, no atomics
    }
    gridbar(flags, 3u);

    // ---- Stage D: reduce Spart columns -> sS (final S); per-edge d2.
    {
        for (int u = tid; u < NN*EDIM; u += 256) {
            float s = 0.f;
            #pragma unroll 8
            for (int b = 0; b < NB; ++b) s += ldG(Spart + u*32 + b);  // independent, pipelined
            sS[u] = s;
        }
        __syncthreads();                 // sDV still valid from stage C
        for (int e = gt; e < EE; e += NB*256) {
            int a = eidx[e], b = eidx[EE + e];
            float da = sDV[a], db = sDV[b];
            float rc = 1.f / (fmaxf(fmaxf(da, db), 0.f) + EPSF);
            float acc = 0.f;
            #pragma unroll
            for (int k = 0; k < EDIM; ++k) {
                float gp = ldG(G + k*EEP + e) * rc;
                float v = fmaf(da, sS[a*EDIM + k] - gp,
                          fmaf(db, sS[b*EDIM + k] - gp, be[k]));
                acc = fmaf(fmaxf(v, 0.f), p2[k], acc);
            }
            stG(d2 + e, acc);
        }
    }
    gridbar(flags, 4u);

    // ---- Stage E: x3 = D2@Y2 + b2; block pool partial -> private Ppart column.
    {
        float* sY = sBuf;
        float* sD = sBuf + 7424;
        float2* sY2p = (float2*)sY;
        for (int u = tid; u < NH/2; u += 256) sY2p[u] = ldG2(Y2 + 2*u);
        float2* sD2p = (float2*)sD;
        for (int u = tid; u < EE/2; u += 256) sD2p[u] = ldG2(d2 + 2*u);
        __syncthreads();
        float acc = b2[lane];
        #pragma unroll 4
        for (int j = 0; j < NN; ++j) {
            int jj = (j == node) ? (j ^ 1) : j;
            float wgt = (j == node) ? 0.f : sD[eid_ij(node, jj)];
            acc = fmaf(wgt, sY[jj*HID + lane], acc);
        }
        sRow[w*HID + lane] = acc;
        __syncthreads();
        if (w == 0) {
            float s4v = sRow[lane] + sRow[HID + lane] + sRow[2*HID + lane] + sRow[3*HID + lane];
            stG(Ppart + lane*32 + blockIdx.x, s4v);      // private column, no atomics
        }
    }
    gridbar(flags, 5u);

    // ---- Stage F: out = (sum Ppart / N) @ Wl + bl (block 0, wave 0).
    if (blockIdx.x == 0 && w == 0) {
        float val = 0.f;
        #pragma unroll 8
        for (int b = 0; b < NB; ++b) val += ldG(Ppart + lane*32 + b);
        val *= (1.0f / NN);
        float res[OUTD];
        #pragma unroll
        for (int o = 0; o < OUTD; ++o) {
            float r = val * Wl[lane*OUTD + o];
            #pragma unroll
            for (int off = 32; off > 0; off >>= 1) r += __shfl_xor(r, off, 64);
            res[o] = r;
        }
        if (lane < OUTD) out[lane] = res[lane] + bl[lane];
    }
}

extern "C" void kernel_launch(void* const* d_in, const int* in_sizes, int n_in,
                              void* d_out, int out_size, void* d_ws, size_t ws_size,
                              hipStream_t stream)
{
    const float* enc   = (const float*)d_in[0];
    const float* ea    = (const float*)d_in[1];
    const int*   eidx  = (const int*)  d_in[2];
    const float* W_enc = (const float*)d_in[3];
    const float* b_enc = (const float*)d_in[4];
    const float* W1    = (const float*)d_in[5];
    const float* b1    = (const float*)d_in[6];
    const float* p1    = (const float*)d_in[7];
    const float* We    = (const float*)d_in[8];
    const float* be    = (const float*)d_in[9];
    const float* pe    = (const float*)d_in[10];
    const float* W2    = (const float*)d_in[11];
    const float* b2    = (const float*)d_in[12];
    const float* p2    = (const float*)d_in[13];
    const float* Wl    = (const float*)d_in[14];
    const float* bl    = (const float*)d_in[15];
    float* ws = (float*)d_ws;

    // Workspace layout (float offsets, 16B-aligned):
    float* Y1    = ws;                 // 7424
    float* Y2    = ws + 7424;          // 7424
    float* d1    = ws + 14848;         // 6672
    float* d2    = ws + 21520;         // 6672
    float* G     = ws + 28192;         // 5*6672 = 33360 (col-major [EDIM][EEP])
    float* dv    = ws + 61552;         // 128
    float* Spart = ws + 61680;         // 580*32 = 18560
    float* Ppart = ws + 80240;         // 64*32  = 2048
    unsigned* flags = (unsigned*)(ws + 82288);   // NB*FSTR uints
    float* out = (float*)d_out;

    hipMemsetAsync(flags, 0, NB * FSTR * sizeof(unsigned), stream);
    fused<<<NB, 256, 0, stream>>>(enc, ea, eidx, W_enc, b_enc, W1, b1, p1, We,
                                  be, pe, W2, b2, p2, Wl, bl,
                                  Y1, Y2, d1, d2, G, dv, Spart, Ppart, flags, out);
}